// Round 11
// baseline (1155.703 us; speedup 1.0000x reference)
//
#include <hip/hip_runtime.h>
#include <math.h>

#define T_LEN 4096
#define FLATD 512
#define HDD 256
#define FEATD 20
#define NCAND 30000
#define HIDD 512
#define KSEL 1638
#define CANT 40
#define MENTD 1300
#define KPAD 1344
#define NPAIR (KSEL*CANT)
#define NEG_INF (-__builtin_inff())

#define MF_RELU 1
#define MF_MASK 4
#define MF_GATE 8

typedef unsigned short u16;
typedef __attribute__((ext_vector_type(8))) short bf16x8;
typedef __attribute__((ext_vector_type(4))) float f32x4;

__device__ __forceinline__ unsigned ordf(float f){
  unsigned u = __float_as_uint(f);
  return (u & 0x80000000u) ? ~u : (u | 0x80000000u);
}
__device__ __forceinline__ float unordf(unsigned u){
  return __uint_as_float((u & 0x80000000u) ? (u ^ 0x80000000u) : ~u);
}
__device__ __forceinline__ float bf2f(u16 h){ return __uint_as_float(((unsigned)h) << 16); }
__device__ __forceinline__ u16 f2bf(float f){
  unsigned u = __float_as_uint(f);
  u += 0x7fffu + ((u >> 16) & 1u);
  return (u16)(u >> 16);
}
__device__ __forceinline__ unsigned pkmul(unsigned a, unsigned b){
  float a0 = __uint_as_float(a << 16), a1 = __uint_as_float(a & 0xffff0000u);
  float b0 = __uint_as_float(b << 16), b1 = __uint_as_float(b & 0xffff0000u);
  float p0 = a0*b0, p1 = a1*b1;
  unsigned r;
  asm("v_cvt_pk_bf16_f32 %0, %1, %2" : "=v"(r) : "v"(p0), "v"(p1));
  return r;
}
// permuted feature layout [start512|end512|hemb256|wemb20|pad44] -> original source row
__device__ __forceinline__ int featsrc(int k){
  if (k < 1024) return k;
  if (k < 1280) return k + 20;
  if (k < 1300) return k - 256;
  return -1;
}
// BK=64 LDS: [rows][64] bf16. Stored slot s of row r holds source slot s^(r&7).
__device__ __forceinline__ int bsrc64(int S){
  return (((S & 7) ^ ((S >> 3) & 7)) << 3);
}
__device__ __forceinline__ int brd64(int row, int h, int k8){
  return row*64 + (((((h << 2) | k8)) ^ (row & 7)) << 3);
}
__device__ __forceinline__ void gload16(const u16* g, u16* l){
  __builtin_amdgcn_global_load_lds((const __attribute__((address_space(1))) void*)(g),
                                   (__attribute__((address_space(3))) void*)(l), 16, 0, 0);
}

// ---------------- prep: flat->bf16, padded wemb(20x64), permuted biases, selws zero ----------------
__global__ __launch_bounds__(256) void k_prep(const float* __restrict__ flat,
    const float* __restrict__ wemb, const float* __restrict__ fast_b, const float* __restrict__ gate_b,
    u16* __restrict__ flatbf, u16* __restrict__ wembP, float* __restrict__ fbP, float* __restrict__ gbP,
    unsigned* __restrict__ selws)
{
  int i = blockIdx.x*256 + threadIdx.x;
  if (i < T_LEN*FLATD) flatbf[i] = f2bf(flat[i]);
  if (i < 20*64) wembP[i] = ((i & 63) < 20) ? f2bf(wemb[(i >> 6)*FEATD + (i & 63)]) : (u16)0;
  if (i < KPAD){
    int s = featsrc(i);
    fbP[i] = (s >= 0) ? fast_b[s] : 0.f;
    gbP[i] = (s >= 0) ? gate_b[s] : 0.f;
  }
  if (i < 6160) selws[i] = 0;
}

// ---------------- head scores ----------------
__global__ __launch_bounds__(256) void k_head(const float* __restrict__ flat,
    const float* __restrict__ w, const float* __restrict__ b, float* __restrict__ hs)
{
  int lane = threadIdx.x & 63, wid = threadIdx.x >> 6;
  int row = blockIdx.x*4 + wid;
  if (row >= T_LEN) return;
  const float* x = flat + (size_t)row*FLATD;
  float s = 0.f;
  for (int j = lane; j < FLATD; j += 64) s += x[j]*w[j];
  #pragma unroll
  for (int o = 32; o; o >>= 1) s += __shfl_down(s, o, 64);
  if (lane == 0) hs[row] = s + b[0];
}

// ------------- per-candidate softmax head embedding -> bf16 (wave per candidate) -------------
__global__ __launch_bounds__(256) void k_cand(const float* __restrict__ hs,
    const float* __restrict__ hdoc, const int* __restrict__ starts, const int* __restrict__ ends,
    u16* __restrict__ hemb)
{
  int wid = threadIdx.x >> 6, lane = threadIdx.x & 63;
  int n = blockIdx.x*4 + wid;
  if (n >= NCAND) return;
  int s = starts[n], e = ends[n];
  int width = e - s + 1;
  float g[20];
  #pragma unroll
  for (int w2 = 0; w2 < 20; ++w2) g[w2] = (w2 < width) ? hs[min(s + w2, T_LEN-1)] : NEG_INF;
  float m = NEG_INF;
  #pragma unroll
  for (int w2 = 0; w2 < 20; ++w2) m = fmaxf(m, g[w2]);
  float sum = 0.f;
  #pragma unroll
  for (int w2 = 0; w2 < 20; ++w2){ g[w2] = expf(g[w2] - m); sum += g[w2]; }
  float inv = 1.f/sum;
  #pragma unroll
  for (int di = 0; di < 4; ++di){
    int d = lane + di*64;
    float acc = 0.f;
    #pragma unroll
    for (int w2 = 0; w2 < 20; ++w2)
      acc += g[w2]*hdoc[(size_t)min(s + w2, T_LEN-1)*HDD + d];
    hemb[(size_t)n*HDD + d] = f2bf(acc*inv);
  }
}

// ------------- batched weight transposes with feature permutation -------------
__global__ __launch_bounds__(256) void k_transall(const float* __restrict__ ms_w1,
    const float* __restrict__ ms_w2, const float* __restrict__ fast_w,
    const float* __restrict__ ss_w1, const float* __restrict__ ss_w2,
    const float* __restrict__ gate_w,
    u16* ms1T, u16* ms2T, u16* fastT, u16* ss1abT, u16* sspT,
    u16* ss2T, u16* gateTall)
{
  const float* B; u16* D; int Kb, N, srcN, ldD, kperm, nperm;
  switch (blockIdx.z){
    case 0: B = ms_w1; D = ms1T; Kb = KPAD; N = HIDD; srcN = HIDD; ldD = KPAD; kperm = 1; nperm = 0; break;
    case 1: B = ms_w2; D = ms2T; Kb = HIDD; N = HIDD; srcN = HIDD; ldD = HIDD; kperm = 0; nperm = 0; break;
    case 2: B = fast_w; D = fastT; Kb = KPAD; N = MENTD; srcN = MENTD; ldD = KPAD; kperm = 1; nperm = 1; break;
    case 3: B = ss_w1; D = ss1abT; Kb = KPAD; N = HIDD; srcN = HIDD; ldD = KPAD; kperm = 1; nperm = 0; break;
    case 4: B = ss_w1 + (size_t)MENTD*HIDD; D = ss1abT + (size_t)512*KPAD; Kb = KPAD; N = HIDD; srcN = HIDD; ldD = KPAD; kperm = 1; nperm = 0; break;
    case 5: B = ss_w1 + (size_t)2*MENTD*HIDD; D = sspT; Kb = KPAD; N = HIDD; srcN = HIDD; ldD = KPAD; kperm = 1; nperm = 0; break;
    case 6: B = ss_w2; D = ss2T; Kb = HIDD; N = HIDD; srcN = HIDD; ldD = HIDD; kperm = 0; nperm = 0; break;
    case 7: B = gate_w; D = gateTall; Kb = KPAD; N = MENTD; srcN = MENTD; ldD = 2*KPAD; kperm = 1; nperm = 1; break;
    default: B = gate_w + (size_t)MENTD*MENTD; D = gateTall + KPAD; Kb = KPAD; N = MENTD; srcN = MENTD; ldD = 2*KPAD; kperm = 1; nperm = 1; break;
  }
  int k0 = blockIdx.x*32, n0 = blockIdx.y*32;
  if (k0 >= Kb || n0 >= N) return;
  __shared__ float t[32][33];
  int tx = threadIdx.x & 31, ty = threadIdx.x >> 5;
  for (int r = ty; r < 32; r += 8){
    int gk = k0 + r, gn = n0 + tx;
    int sk = kperm ? featsrc(gk) : ((gk < Kb) ? gk : -1);
    int sn = nperm ? ((gn < N) ? featsrc(gn) : -1) : ((gn < N) ? gn : -1);
    t[r][tx] = (sk >= 0 && sn >= 0) ? B[(size_t)sk*srcN + sn] : 0.f;
  }
  __syncthreads();
  for (int r = ty; r < 32; r += 8){
    int gn = n0 + r, gk = k0 + tx;
    if (gn < N && gk < Kb) D[(size_t)gn*ldD + gk] = f2bf(t[tx][r]);
  }
}

// ------- mention-scorer layer1: A rows built on the fly, BK=64, gload_lds -------
__global__ __launch_bounds__(256) void k_mfma_cand(
    const u16* __restrict__ flatbf, const u16* __restrict__ hemb, const u16* __restrict__ wembP,
    const int* __restrict__ starts, const int* __restrict__ ends,
    const u16* __restrict__ Bt, int M, const float* __restrict__ bias, u16* __restrict__ Cbf)
{
  __shared__ alignas(16) u16 As[8192];
  __shared__ alignas(16) u16 Bs[8192];
  int tid = threadIdx.x;
  int row0 = blockIdx.y*128, col0 = blockIdx.x*128;
  int lane = tid & 63, wid = tid >> 6;
  int wr = wid >> 1, wc = wid & 1;
  int l15 = lane & 15, l4 = lane >> 4;

  int sS[4], eS[4], nS[4], so[4];
  const u16* pb[4];
  #pragma unroll
  for (int i = 0; i < 4; ++i){
    int S = tid + (i << 8);
    int r = S >> 3;
    so[i] = bsrc64(S);
    int n = row0 + r; if (n >= M) n = M - 1;
    sS[i] = starts[n]; eS[i] = ends[n]; nS[i] = n;
    pb[i] = Bt + (size_t)(col0 + r)*KPAD + so[i];
  }

  f32x4 acc[4][4];
  #pragma unroll
  for (int m = 0; m < 4; ++m)
    #pragma unroll
    for (int n = 0; n < 4; ++n)
      #pragma unroll
      for (int q = 0; q < 4; ++q) acc[m][n][q] = 0.f;

  for (int kt = 0; kt < KPAD/64; ++kt){
    int k0 = kt << 6;
    #pragma unroll
    for (int i = 0; i < 4; ++i){
      int f = k0 + so[i];
      const u16* src = (f < 512) ? flatbf + (size_t)sS[i]*FLATD + f
                     : (f < 1024) ? flatbf + (size_t)eS[i]*FLATD + (f - 512)
                     : (f < 1280) ? hemb + (size_t)nS[i]*HDD + (f - 1024)
                     : wembP + (eS[i] - sS[i])*64 + (f - 1280);
      gload16(src, As + (tid + (i << 8))*8);
      gload16(pb[i] + k0, Bs + (tid + (i << 8))*8);
    }
    __syncthreads();
    #pragma unroll
    for (int h = 0; h < 2; ++h){
      bf16x8 af[4], bfr[4];
      #pragma unroll
      for (int m = 0; m < 4; ++m) af[m] = *(const bf16x8*)(As + brd64(wr*64 + m*16 + l15, h, l4));
      #pragma unroll
      for (int n = 0; n < 4; ++n) bfr[n] = *(const bf16x8*)(Bs + brd64(wc*64 + n*16 + l15, h, l4));
      #pragma unroll
      for (int m = 0; m < 4; ++m)
        #pragma unroll
        for (int n = 0; n < 4; ++n)
          acc[m][n] = __builtin_amdgcn_mfma_f32_16x16x32_bf16(af[m], bfr[n], acc[m][n], 0, 0, 0);
    }
    __syncthreads();
  }
  #pragma unroll
  for (int m = 0; m < 4; ++m){
    #pragma unroll
    for (int q = 0; q < 4; ++q){
      int grow = row0 + wr*64 + m*16 + l4*4 + q;
      if (grow >= M) continue;
      #pragma unroll
      for (int n = 0; n < 4; ++n){
        int gcol = col0 + wc*64 + n*16 + l15;
        float v = fmaxf(acc[m][n][q] + bias[gcol], 0.f);
        Cbf[(size_t)grow*HIDD + gcol] = f2bf(v);
      }
    }
  }
}

// ---------------- generic bf16 MFMA GEMM, BK=64 (global_load_lds staging) ----------------
__global__ __launch_bounds__(256) void k_mfma(const u16* __restrict__ A,
    const u16* __restrict__ A2, const u16* __restrict__ Bt, int M, int N, int Kp, int ldA,
    const float* __restrict__ bias, const float* __restrict__ msc,
    float* __restrict__ Cf, int ldf, u16* __restrict__ Cbf, int ldbf, int Nstore, int flags,
    const u16* __restrict__ g_att, const u16* __restrict__ g_mo)
{
  __shared__ alignas(16) u16 As[8192];
  __shared__ alignas(16) u16 Bs[8192];
  int tid = threadIdx.x;
  int row0 = blockIdx.y*128, col0 = blockIdx.x*128;
  if ((flags & MF_MASK) && col0 >= row0 + 128) return;
  int lane = tid & 63, wid = tid >> 6;
  int wr = wid >> 1, wc = wid & 1;
  int l15 = lane & 15, l4 = lane >> 4;

  const u16 *pa[4], *qa[4], *pb[4];
  int kt1 = A2 ? (ldA >> 6) : (Kp >> 6);
  int koff = kt1 << 6;
  #pragma unroll
  for (int i = 0; i < 4; ++i){
    int S = tid + (i << 8);
    int r = S >> 3;
    int soi = bsrc64(S);
    int ra = row0 + r; if (ra >= M) ra = M - 1;
    int cb = col0 + r; if (cb >= N) cb = N - 1;
    pa[i] = A + (size_t)ra*ldA + soi;
    qa[i] = A2 ? (A2 + (size_t)ra*ldA + soi - koff) : pa[i];
    pb[i] = Bt + (size_t)cb*Kp + soi;
  }

  f32x4 acc[4][4];
  #pragma unroll
  for (int m = 0; m < 4; ++m)
    #pragma unroll
    for (int n = 0; n < 4; ++n)
      #pragma unroll
      for (int q = 0; q < 4; ++q) acc[m][n][q] = 0.f;

  int nkt = Kp >> 6;
  for (int kt = 0; kt < nkt; ++kt){
    int k0 = kt << 6;
    #pragma unroll
    for (int i = 0; i < 4; ++i){
      const u16* a = (kt < kt1) ? pa[i] : qa[i];
      gload16(a + k0, As + (tid + (i << 8))*8);
      gload16(pb[i] + k0, Bs + (tid + (i << 8))*8);
    }
    __syncthreads();
    #pragma unroll
    for (int h = 0; h < 2; ++h){
      bf16x8 af[4], bfr[4];
      #pragma unroll
      for (int m = 0; m < 4; ++m) af[m] = *(const bf16x8*)(As + brd64(wr*64 + m*16 + l15, h, l4));
      #pragma unroll
      for (int n = 0; n < 4; ++n) bfr[n] = *(const bf16x8*)(Bs + brd64(wc*64 + n*16 + l15, h, l4));
      #pragma unroll
      for (int m = 0; m < 4; ++m)
        #pragma unroll
        for (int n = 0; n < 4; ++n)
          acc[m][n] = __builtin_amdgcn_mfma_f32_16x16x32_bf16(af[m], bfr[n], acc[m][n], 0, 0, 0);
    }
    __syncthreads();
  }
  #pragma unroll
  for (int m = 0; m < 4; ++m){
    #pragma unroll
    for (int q = 0; q < 4; ++q){
      int grow = row0 + wr*64 + m*16 + l4*4 + q;
      if (grow >= M) continue;
      #pragma unroll
      for (int n = 0; n < 4; ++n){
        int gcol = col0 + wc*64 + n*16 + l15;
        if (gcol < N){
          float v = acc[m][n][q];
          if (bias) v += bias[gcol];
          if (flags & MF_MASK){ v += msc[grow] + msc[gcol]; if (gcol >= grow) v = NEG_INF; }
          if (flags & MF_RELU) v = fmaxf(v, 0.f);
          if (flags & MF_GATE){
            float f = 1.f/(1.f + expf(-v));
            float res = f*bf2f(g_att[(size_t)grow*ldbf + gcol])
                      + (1.f - f)*bf2f(g_mo[(size_t)grow*ldbf + gcol]);
            Cbf[(size_t)grow*ldbf + gcol] = f2bf(res);
          } else {
            if (Cf)  Cf[(size_t)grow*ldf + gcol] = v;
            if (Cbf) Cbf[(size_t)grow*ldbf + gcol] = f2bf(v);
          }
        } else if (Cbf && gcol < Nstore){
          Cbf[(size_t)grow*ldbf + gcol] = 0;
        }
      }
    }
  }
}

// ---- fused layer2 + w3 dot, 4 col-panels of 128, BK=64 (R8-proven) ----
__global__ __launch_bounds__(256) void k_mfma_rowdot(const u16* __restrict__ A,
    const u16* __restrict__ Bt, int M, const float* __restrict__ b2,
    const float* __restrict__ w3, const float* __restrict__ b3,
    const float* __restrict__ add, float* __restrict__ out)
{
  __shared__ alignas(16) u16 As[8192];
  __shared__ alignas(16) u16 Bs[8192];
  __shared__ float rsum[128][2];
  int tid = threadIdx.x;
  int row0 = blockIdx.x*128;
  int lane = tid & 63, wid = tid >> 6;
  int wr = wid >> 1, wc = wid & 1;
  int l15 = lane & 15, l4 = lane >> 4;

  const u16* pa[4]; int so[4], rr[4];
  #pragma unroll
  for (int i = 0; i < 4; ++i){
    int S = tid + (i << 8);
    int r = S >> 3;
    so[i] = bsrc64(S); rr[i] = r;
    int ra = row0 + r; if (ra >= M) ra = M - 1;
    pa[i] = A + (size_t)ra*HIDD + so[i];
  }

  float rd[4][4] = {};
  for (int p = 0; p < 4; ++p){
    int col0 = p*128;
    f32x4 acc[4][4];
    #pragma unroll
    for (int m = 0; m < 4; ++m)
      #pragma unroll
      for (int n = 0; n < 4; ++n)
        #pragma unroll
        for (int q = 0; q < 4; ++q) acc[m][n][q] = 0.f;
    for (int kt = 0; kt < HIDD/64; ++kt){
      int k0 = kt << 6;
      #pragma unroll
      for (int i = 0; i < 4; ++i){
        gload16(pa[i] + k0, As + (tid + (i << 8))*8);
        gload16(Bt + (size_t)(col0 + rr[i])*HIDD + so[i] + k0, Bs + (tid + (i << 8))*8);
      }
      __syncthreads();
      #pragma unroll
      for (int h = 0; h < 2; ++h){
        bf16x8 af[4], bfr[4];
        #pragma unroll
        for (int m = 0; m < 4; ++m) af[m] = *(const bf16x8*)(As + brd64(wr*64 + m*16 + l15, h, l4));
        #pragma unroll
        for (int n = 0; n < 4; ++n) bfr[n] = *(const bf16x8*)(Bs + brd64(wc*64 + n*16 + l15, h, l4));
        #pragma unroll
        for (int m = 0; m < 4; ++m)
          #pragma unroll
          for (int n = 0; n < 4; ++n)
            acc[m][n] = __builtin_amdgcn_mfma_f32_16x16x32_bf16(af[m], bfr[n], acc[m][n], 0, 0, 0);
      }
      __syncthreads();
    }
    #pragma unroll
    for (int n = 0; n < 4; ++n){
      int gcol = col0 + wc*64 + n*16 + l15;
      float bb = b2[gcol], ww = w3[gcol];
      #pragma unroll
      for (int m = 0; m < 4; ++m)
        #pragma unroll
        for (int q = 0; q < 4; ++q){
          float v = fmaxf(acc[m][n][q] + bb, 0.f);
          rd[m][q] = fmaf(v, ww, rd[m][q]);
        }
    }
  }
  #pragma unroll
  for (int m = 0; m < 4; ++m)
    #pragma unroll
    for (int q = 0; q < 4; ++q){
      float s = rd[m][q];
      s += __shfl_xor(s, 1, 64); s += __shfl_xor(s, 2, 64);
      s += __shfl_xor(s, 4, 64); s += __shfl_xor(s, 8, 64);
      if (l15 == 0) rsum[wr*64 + m*16 + l4*4 + q][wc] = s;
    }
  __syncthreads();
  if (tid < 128){
    int gr = row0 + tid;
    if (gr < M){
      float v = rsum[tid][0] + rsum[tid][1] + b3[0];
      if (add) v += add[gr];
      out[gr] = v;
    }
  }
}

// ------- pair layer1 MFMA: 128x256 tile, BK=64, staged on-the-fly product A (R8-proven) -------
__global__ __launch_bounds__(256, 2) void k_d1_mfma(int Mc,
    const u16* __restrict__ ment, const int* __restrict__ antes, const int* __restrict__ mspk,
    const u16* __restrict__ Bt, const float* __restrict__ A_meb,
    const float* __restrict__ comb, u16* __restrict__ H1)
{
  __shared__ alignas(16) u16 As[8192];    // 128 rows x 64
  __shared__ alignas(16) u16 Bs[16384];   // 256 cols x 64
  __shared__ int ri[128], rj[128], rcomb[128];
  int tid = threadIdx.x;
  int row0 = blockIdx.y*128;
  int col0 = blockIdx.x*256;
  if (tid < 128){
    int r = row0 + tid;
    int p = (r < Mc ? r : 0);
    int i = p / CANT;
    int j = antes[p];
    ri[tid] = i; rj[tid] = j;
    int same = (mspk[i] == mspk[j]) ? 1 : 0;
    int d = i - j; d = d < 0 ? 0 : (d > 64 ? 64 : d);
    int bin = (d <= 4) ? d : (d <= 8 ? 5 : (d <= 16 ? 6 : (d <= 32 ? 7 : 8)));
    rcomb[tid] = same*9 + bin;
  }
  __syncthreads();
  int lane = tid & 63, wid = tid >> 6;
  int wr = wid >> 1, wc = wid & 1;
  int l15 = lane & 15, l4 = lane >> 4;

  const u16 *pi[4], *pj[4];
  #pragma unroll
  for (int i = 0; i < 4; ++i){
    int S = tid + (i << 8);
    int r = S >> 3;
    int soi = bsrc64(S);
    pi[i] = ment + (size_t)ri[r]*KPAD + soi;
    pj[i] = ment + (size_t)rj[r]*KPAD + soi;
  }
  int bo[8];
  #pragma unroll
  for (int i = 0; i < 8; ++i){
    int S = tid + (i << 8);
    int r = S >> 3;
    bo[i] = (col0 + r)*KPAD + bsrc64(S);
  }

  f32x4 acc[4][8];
  #pragma unroll
  for (int m = 0; m < 4; ++m)
    #pragma unroll
    for (int n = 0; n < 8; ++n)
      #pragma unroll
      for (int q = 0; q < 4; ++q) acc[m][n][q] = 0.f;

  int nkt = KPAD >> 6;
  for (int kt = 0; kt < nkt; ++kt){
    int k0 = kt << 6;
    #pragma unroll
    for (int i = 0; i < 8; ++i)
      gload16(Bt + bo[i] + k0, Bs + (tid + (i << 8))*8);
    #pragma unroll
    for (int i = 0; i < 4; ++i){
      uint4 va = *(const uint4*)(pi[i] + k0);
      uint4 vb = *(const uint4*)(pj[i] + k0);
      uint4 vo;
      vo.x = pkmul(va.x, vb.x); vo.y = pkmul(va.y, vb.y);
      vo.z = pkmul(va.z, vb.z); vo.w = pkmul(va.w, vb.w);
      *(uint4*)(As + (tid + (i << 8))*8) = vo;
    }
    __syncthreads();
    #pragma unroll
    for (int h = 0; h < 2; ++h){
      bf16x8 af[4];
      #pragma unroll
      for (int m = 0; m < 4; ++m) af[m] = *(const bf16x8*)(As + brd64(wr*64 + m*16 + l15, h, l4));
      #pragma unroll
      for (int n = 0; n < 8; ++n){
        bf16x8 bfr = *(const bf16x8*)(Bs + brd64(wc*128 + n*16 + l15, h, l4));
        #pragma unroll
        for (int m = 0; m < 4; ++m)
          acc[m][n] = __builtin_amdgcn_mfma_f32_16x16x32_bf16(af[m], bfr, acc[m][n], 0, 0, 0);
      }
    }
    __syncthreads();
  }
  #pragma unroll
  for (int m = 0; m < 4; ++m){
    #pragma unroll
    for (int q = 0; q < 4; ++q){
      int rl = wr*64 + m*16 + l4*4 + q;
      int grow = row0 + rl;
      if (grow >= Mc) continue;
      const float* me = A_meb + (size_t)ri[rl]*1024;
      const float* an = A_meb + (size_t)rj[rl]*1024 + 512;
      const float* cb = comb + (size_t)rcomb[rl]*HIDD;
      #pragma unroll
      for (int n = 0; n < 8; ++n){
        int gcol = col0 + wc*128 + n*16 + l15;
        float v = acc[m][n][q] + me[gcol] + an[gcol] + cb[gcol];
        H1[(size_t)grow*HIDD + gcol] = f2bf(fmaxf(v, 0.f));
      }
    }
  }
}

// ================= top-K selection pipeline (fused last-block thresholds) =================
// selws: [0..2047] binA | [2048..4095] binB | [4096..6143] binC | 6144..6149 meta | 6152,6153 cnt
//        6156..6158 hist tickets | 6159 compact ticket
__global__ __launch_bounds__(256) void k_hist(const float* __restrict__ scores,
    unsigned* __restrict__ selws, int pass)
{
  int n = blockIdx.x*256 + threadIdx.x;
  unsigned* meta = selws + 6144;
  if (n < NCAND){
    unsigned u = ordf(scores[n]);
    if (pass == 0) atomicAdd(&selws[u >> 21], 1u);
    else if (pass == 1){ if ((u >> 21) == meta[0]) atomicAdd(&selws[2048 + ((u >> 10) & 0x7FFu)], 1u); }
    else { if ((u >> 10) == meta[2]) atomicAdd(&selws[4096 + (u & 0x3FFu)], 1u); }
  }
  __syncthreads();
  __shared__ unsigned lastflag;
  if (threadIdx.x == 0){
    __threadfence();
    unsigned t = atomicAdd(&selws[6156 + pass], 1u);
    lastflag = (t == gridDim.x - 1) ? 1u : 0u;
  }
  __syncthreads();
  if (!lastflag) return;
  __threadfence();
  // suffix-scan the 2048 bins with 256 threads
  __shared__ unsigned a[2048], b[2048];
  const unsigned* gbin = selws + (pass == 0 ? 0 : (pass == 1 ? 2048 : 4096));
  for (int i = threadIdx.x; i < 2048; i += 256) a[i] = gbin[i];
  unsigned *src = a, *dst = b;
  for (int step = 1; step < 2048; step <<= 1){
    __syncthreads();
    for (int i = threadIdx.x; i < 2048; i += 256)
      dst[i] = src[i] + ((i + step < 2048) ? src[i + step] : 0u);
    unsigned* t2 = src; src = dst; dst = t2;
  }
  __syncthreads();
  unsigned target = (pass == 0) ? (unsigned)KSEL : meta[pass == 1 ? 1 : 3];
  for (int i = threadIdx.x; i < 2048; i += 256){
    unsigned si = src[i], sn = (i < 2047) ? src[i+1] : 0u;
    if (si >= target && sn < target){
      if (pass == 0){ meta[0] = (unsigned)i; meta[1] = target - sn; }
      else if (pass == 1){ meta[2] = (meta[0] << 11) | (unsigned)i; meta[3] = target - sn; }
      else { meta[4] = (meta[2] << 10) | (unsigned)i; meta[5] = target - sn; }
    }
  }
}
__global__ __launch_bounds__(256) void k_compact(const float* __restrict__ scores,
    unsigned* __restrict__ selws, int* __restrict__ g_sel, unsigned* __restrict__ g_eq)
{
  int n = blockIdx.x*256 + threadIdx.x;
  unsigned kth = selws[6144 + 4];
  unsigned* cnt = selws + 6152;
  if (n < NCAND){
    unsigned u = ordf(scores[n]);
    if (u > kth){ unsigned p = atomicAdd(&cnt[0], 1u); g_sel[p] = n; }
    else if (u == kth){ unsigned p = atomicAdd(&cnt[1], 1u); if (p < 1024) g_eq[p] = (unsigned)n; }
  }
  __syncthreads();
  __shared__ unsigned lastflag;
  if (threadIdx.x == 0){
    __threadfence();
    unsigned t = atomicAdd(&selws[6159], 1u);
    lastflag = (t == gridDim.x - 1) ? 1u : 0u;
  }
  __syncthreads();
  if (!lastflag) return;
  __threadfence();
  // eqrank in this block
  __shared__ unsigned eq[1024];
  unsigned neq = selws[6153]; if (neq > 1024u) neq = 1024u;
  unsigned E = selws[6144 + 5];
  unsigned G = selws[6152];
  for (int t = threadIdx.x; t < 1024; t += 256) eq[t] = (t < (int)neq) ? g_eq[t] : 0xFFFFFFFFu;
  __syncthreads();
  for (int t = threadIdx.x; t < (int)neq; t += 256){
    unsigned mine = eq[t]; unsigned r = 0;
    for (unsigned j = 0; j < neq; ++j) r += (eq[j] < mine) ? 1u : 0u;
    if (r < E) g_sel[G + r] = (int)mine;
  }
}
__global__ __launch_bounds__(256) void k_rank1(const float* __restrict__ scores,
    const int* __restrict__ g_sel, int* __restrict__ ranked)
{
  __shared__ unsigned long long key[KSEL];
  int tid = threadIdx.x;
  for (int t = tid; t < KSEL; t += 256){
    int n = g_sel[t];
    key[t] = ((unsigned long long)(~ordf(scores[n])) << 32) | (unsigned)n;
  }
  __syncthreads();
  int t = blockIdx.x*256 + tid;
  if (t >= KSEL) return;
  unsigned long long mine = key[t];
  int r = 0;
  #pragma unroll 16
  for (int j = 0; j < KSEL; ++j) r += (key[j] < mine) ? 1 : 0;
  ranked[r] = (int)(mine & 0xFFFFFFFFu);
}
__global__ __launch_bounds__(256) void k_rank2(const int* __restrict__ ranked,
    const int* __restrict__ starts, const int* __restrict__ ends, int* __restrict__ top_idx)
{
  __shared__ unsigned long long key[KSEL];
  int tid = threadIdx.x;
  int elast = ends[NCAND-1];
  for (int t = tid; t < KSEL; t += 256){
    int n = ranked[t];
    unsigned mp = (unsigned)(starts[n]*elast + ends[n]);
    key[t] = ((unsigned long long)mp << 11) | (unsigned)t;
  }
  __syncthreads();
  int t = blockIdx.x*256 + tid;
  if (t >= KSEL) return;
  unsigned long long mine = key[t];
  int r = 0;
  #pragma unroll 16
  for (int j = 0; j < KSEL; ++j) r += (key[j] < mine) ? 1 : 0;
  top_idx[r] = ranked[t];
}

// ---------------- gather mention rows -> bf16 [KSEL][KPAD], permuted layout ----------------
__global__ __launch_bounds__(256) void k_gather(const int* __restrict__ top_idx,
    const u16* __restrict__ flatbf, const u16* __restrict__ hemb, const u16* __restrict__ wembP,
    const int* __restrict__ starts, const int* __restrict__ ends,
    const float* __restrict__ cscores, const int* __restrict__ spk_ids,
    u16* __restrict__ ment, float* __restrict__ mscore, int* __restrict__ mspk)
{
  int k = blockIdx.x; int n = top_idx[k];
  int s = starts[n], e = ends[n];
  int v = threadIdx.x;
  if (v < KPAD/8){
    int f0 = v*8;
    const u16* src = (f0 < 512) ? flatbf + (size_t)s*FLATD + f0
                   : (f0 < 1024) ? flatbf + (size_t)e*FLATD + (f0 - 512)
                   : (f0 < 1280) ? hemb + (size_t)n*HDD + (f0 - 1024)
                   : wembP + (e - s)*64 + (f0 - 1280);
    *(uint4*)(ment + (size_t)k*KPAD + f0) = *(const uint4*)src;
  }
  if (threadIdx.x == 0){ mscore[k] = cscores[n]; mspk[k] = spk_ids[s]; }
}

// ---------------- per-row top-40, wave-per-row, register keys ----------------
__global__ __launch_bounds__(256) void k_f3(const float* __restrict__ fast,
    float* __restrict__ top_fast, int* __restrict__ antes)
{
  int wid = threadIdx.x >> 6, lane = threadIdx.x & 63;
  int i = blockIdx.x*4 + wid;
  if (i >= KSEL) return;
  const float* row = fast + (size_t)i*KSEL;
  unsigned long long key[26];
  #pragma unroll
  for (int t = 0; t < 26; ++t){
    int j = lane + (t << 6);
    unsigned long long k2 = 0ULL;
    if (j < i) k2 = ((unsigned long long)ordf(row[j]) << 32) | (unsigned)(0xFFFFFFFFu - (unsigned)j);
    key[t] = k2;
  }
  for (int c = 0; c < CANT; ++c){
    unsigned long long m = 0ULL;
    #pragma unroll
    for (int t = 0; t < 26; ++t) if (key[t] > m) m = key[t];
    #pragma unroll
    for (int o = 32; o; o >>= 1){
      unsigned long long v = __shfl_xor(m, o, 64);
      if (v > m) m = v;
    }
    if (m){
      #pragma unroll
      for (int t = 0; t < 26; ++t) if (key[t] == m) key[t] = 0ULL;
    }
    if (lane == 0){
      if (m){
        top_fast[(size_t)i*CANT + c] = unordf((unsigned)(m >> 32));
        antes[(size_t)i*CANT + c]    = (int)(0xFFFFFFFFu - (unsigned)(m & 0xFFFFFFFFu));
      } else {
        top_fast[(size_t)i*CANT + c] = NEG_INF;
        antes[(size_t)i*CANT + c]    = c;
      }
    }
  }
}

// ------- comb[same*9+bin][512]: (spk+genre+dist) rows through ss_w1 + b1, pre-summed -------
__global__ __launch_bounds__(256) void k_dsmall(const float* __restrict__ ss_w1,
    const float* __restrict__ ss_b1, const float* __restrict__ spk_emb,
    const float* __restrict__ gen_emb, const float* __restrict__ dist_emb,
    const int* __restrict__ genre_id, float* __restrict__ comb)
{
  int r = blockIdx.x;             // 0..17
  int same = r / 9, bin = r % 9;
  const float* es = spk_emb + same*FEATD;
  const float* eg = gen_emb + genre_id[0]*FEATD;
  const float* ed = dist_emb + bin*FEATD;
  for (int h = threadIdx.x; h < HIDD; h += 256){
    float acc = ss_b1[h];
    const float* ws_ = ss_w1 + (size_t)3900*HIDD + h;
    const float* wg  = ss_w1 + (size_t)3920*HIDD + h;
    const float* wd  = ss_w1 + (size_t)3940*HIDD + h;
    for (int f = 0; f < FEATD; ++f){
      acc += es[f]*ws_[(size_t)f*HIDD];
      acc += eg[f]*wg[(size_t)f*HIDD];
      acc += ed[f]*wd[(size_t)f*HIDD];
    }
    comb[(size_t)r*HIDD + h] = acc;
  }
}

// ---------------- softmax over [0, ante_scores] + attended -> bf16 (vectorized) ----------------
__global__ __launch_bounds__(256) void k_d4a(const float* __restrict__ ante_sc,
    const int* __restrict__ antes, const u16* __restrict__ ment, u16* __restrict__ att_bf)
{
  int i = blockIdx.x;
  __shared__ float w[CANT+1];
  __shared__ int aj[CANT];
  if (threadIdx.x == 0){
    float s[CANT]; float m = 0.f;
    #pragma unroll
    for (int c = 0; c < CANT; ++c){ s[c] = ante_sc[i*CANT + c]; m = fmaxf(m, s[c]); }
    float e0 = expf(0.f - m);
    float sum = e0;
    float ex[CANT];
    #pragma unroll
    for (int c = 0; c < CANT; ++c){ ex[c] = expf(s[c] - m); sum += ex[c]; }
    float inv = 1.f/sum;
    w[0] = e0*inv;
    #pragma unroll
    for (int c = 0; c < CANT; ++c) w[c+1] = ex[c]*inv;
  }
  if (threadIdx.x < CANT) aj[threadIdx.x] = antes[i*CANT + threadIdx.x];
  __syncthreads();
  int v = threadIdx.x;
  if (v >= KPAD/8) return;
  int d0 = v*8;
  float r[8] = {};
  {
    uint4 x = *(const uint4*)(ment + (size_t)i*KPAD + d0);
    float w0 = w[0];
    const unsigned* px = (const unsigned*)&x;
    #pragma unroll
    for (int h = 0; h < 4; ++h){
      r[2*h]   = w0*__uint_as_float(px[h] << 16);
      r[2*h+1] = w0*__uint_as_float(px[h] & 0xffff0000u);
    }
  }
  for (int c = 0; c < CANT; ++c){
    uint4 x = *(const uint4*)(ment + (size_t)aj[c]*KPAD + d0);
    float wc_ = w[c+1];
    const unsigned* px = (const unsigned*)&x;
    #pragma unroll
    for (int h = 0; h < 4; ++h){
      r[2*h]   = fmaf(wc_, __uint_as_float(px[h] << 16), r[2*h]);
      r[2*h+1] = fmaf(wc_, __uint_as_float(px[h] & 0xffff0000u), r[2*h+1]);
    }
  }
  u16 o[8];
  #pragma unroll
  for (int h = 0; h < 8; ++h) o[h] = f2bf(r[h]);
  *(uint4*)(att_bf + (size_t)i*KPAD + d0) = *(const uint4*)o;
}

// ---------------- final output (sanitize non-finite) ----------------
__global__ __launch_bounds__(256) void k_out(const float* __restrict__ ante_sc, float* __restrict__ out){
  int idx = blockIdx.x*256 + threadIdx.x;
  if (idx >= KSEL*41) return;
  int i = idx / 41, c = idx % 41;
  float v = (c == 0) ? 0.f : ante_sc[i*CANT + (c-1)];
  if (!isfinite(v)) v = -3.0e38f;
  out[idx] = v;
}

__global__ void k_zero(float* out, int n){
  int i = blockIdx.x*256 + threadIdx.x;
  if (i < n) out[i] = 0.f;
}

extern "C" void kernel_launch(void* const* d_in, const int* in_sizes, int n_in,
                              void* d_out, int out_size, void* d_ws, size_t ws_size,
                              hipStream_t stream)
{
  const float* flat   = (const float*)d_in[0];
  const float* hdoc   = (const float*)d_in[1];
  const float* w_head = (const float*)d_in[2];
  const float* b_head = (const float*)d_in[3];
  const float* wemb   = (const float*)d_in[4];
  const float* ms_w1  = (const float*)d_in[5];
  const float* ms_b1  = (const float*)d_in[6];
  const float* ms_w2  = (const float*)d_in[7];
  const float* ms_b2  = (const float*)d_in[8];
  const float* ms_w3  = (const float*)d_in[9];
  const float* ms_b3  = (const float*)d_in[10];
  const float* fast_w = (const float*)d_in[11];
  const float* fast_b = (const float*)d_in[12];
  const float* ss_w1  = (const float*)d_in[13];
  const float* ss_b1  = (const float*)d_in[14];
  const float* ss_w2  = (const float*)d_in[15];
  const float* ss_b2  = (const float*)d_in[16];
  const float* ss_w3  = (const float*)d_in[17];
  const float* ss_b3  = (const float*)d_in[18];
  const float* gate_w = (const float*)d_in[19];
  const float* gate_b = (const float*)d_in[20];
  const float* spk_e  = (const float*)d_in[21];
  const float* gen_e  = (const float*)d_in[22];
  const float* dist_e = (const float*)d_in[23];
  const int* starts   = (const int*)d_in[24];
  const int* ends     = (const int*)d_in[25];
  const int* spk_ids  = (const int*)d_in[26];
  const int* genre_id = (const int*)d_in[27];
  float* out = (float*)d_out;

  size_t off = 0;
  char* base = (char*)d_ws;
  auto alloc = [&](size_t nbytes) -> void* {
    void* p = (void*)(base + off);
    off += ((nbytes + 255)/256)*256;
    return p;
  };
  float* head_sc = (float*)alloc((size_t)T_LEN*4);
  u16*   flatbf  = (u16*)alloc((size_t)T_LEN*FLATD*2);
  u16*   wembP   = (u16*)alloc((size_t)20*64*2);
  float* fbP     = (float*)alloc((size_t)KPAD*4);
  float* gbP     = (float*)alloc((size_t)KPAD*4);
  u16*   hemb    = (u16*)alloc((size_t)NCAND*HDD*2);
  float* cscores = (float*)alloc((size_t)NCAND*4);
  int*   top_idx = (int*)alloc(2048*4);
  unsigned* selws= (unsigned*)alloc(6160*4);
  int*   g_sel   = (int*)alloc((size_t)KSEL*4);
  unsigned* g_eq = (unsigned*)alloc(1024*4);
  int*   g_rank  = (int*)alloc((size_t)KSEL*4);
  u16*   ms1T    = (u16*)alloc((size_t)HIDD*KPAD*2);
  u16*   ms2T    = (u16*)alloc((size_t)HIDD*HIDD*2);
  u16*   fastT   = (u16*)alloc((size_t)MENTD*KPAD*2);
  u16*   ss1abT  = (u16*)alloc((size_t)1024*KPAD*2);
  u16*   sspT    = (u16*)alloc((size_t)HIDD*KPAD*2);
  u16*   ss2T    = (u16*)alloc((size_t)HIDD*HIDD*2);
  u16*   gateTall= (u16*)alloc((size_t)MENTD*2*KPAD*2);
  u16*   ment    = (u16*)alloc((size_t)KSEL*KPAD*2);
  u16*   mentB   = (u16*)alloc((size_t)KSEL*KPAD*2);
  u16*   srcb    = (u16*)alloc((size_t)KSEL*KPAD*2);
  float* mscore  = (float*)alloc((size_t)KSEL*4);
  int*   mspk    = (int*)alloc((size_t)KSEL*4);
  float* fastm   = (float*)alloc((size_t)KSEL*KSEL*4);
  float* top_fast= (float*)alloc((size_t)NPAIR*4);
  int*   antes   = (int*)alloc((size_t)NPAIR*4);
  float* ante_sc = (float*)alloc((size_t)NPAIR*4);
  float* A_meb   = (float*)alloc((size_t)KSEL*1024*4);
  float* comb    = (float*)alloc((size_t)18*HIDD*4);
  u16*   att_bf  = (u16*)alloc((size_t)KSEL*KPAD*2);
  u16*   bufH1   = (u16*)alloc((size_t)NPAIR*HIDD*2);

  if (ws_size < off){
    k_zero<<<(KSEL*41 + 255)/256, 256, 0, stream>>>(out, KSEL*41);
    return;
  }

  k_prep<<<(T_LEN*FLATD + 255)/256, 256, 0, stream>>>(flat, wemb, fast_b, gate_b,
                                                      flatbf, wembP, fbP, gbP, selws);
  k_transall<<<dim3(KPAD/32, 41, 9), 256, 0, stream>>>(ms_w1, ms_w2, fast_w, ss_w1, ss_w2, gate_w,
      ms1T, ms2T, fastT, ss1abT, sspT, ss2T, gateTall);

  k_head<<<T_LEN/4, 256, 0, stream>>>(flat, w_head, b_head, head_sc);
  k_cand<<<NCAND/4, 256, 0, stream>>>(head_sc, hdoc, starts, ends, hemb);

  // mention scorer (single pass over 30000 rows)
  k_mfma_cand<<<dim3(HIDD/128, (NCAND + 127)/128), 256, 0, stream>>>(
      flatbf, hemb, wembP, starts, ends, ms1T, NCAND, ms_b1, bufH1);
  k_mfma_rowdot<<<(NCAND + 127)/128, 256, 0, stream>>>(bufH1, ms2T, NCAND, ms_b2, ms_w3, ms_b3,
                                                       nullptr, cscores);

  // top-K selection pipeline (fused thresholds)
  k_hist<<<(NCAND + 255)/256, 256, 0, stream>>>(cscores, selws, 0);
  k_hist<<<(NCAND + 255)/256, 256, 0, stream>>>(cscores, selws, 1);
  k_hist<<<(NCAND + 255)/256, 256, 0, stream>>>(cscores, selws, 2);
  k_compact<<<(NCAND + 255)/256, 256, 0, stream>>>(cscores, selws, g_sel, g_eq);
  k_rank1<<<(KSEL + 255)/256, 256, 0, stream>>>(cscores, g_sel, g_rank);
  k_rank2<<<(KSEL + 255)/256, 256, 0, stream>>>(g_rank, starts, ends, top_idx);

  k_gather<<<KSEL, 256, 0, stream>>>(top_idx, flatbf, hemb, wembP, starts, ends, cscores, spk_ids,
                                     ment, mscore, mspk);

  // fast antecedent scores
  k_mfma<<<dim3((MENTD+127)/128, (KSEL+127)/128), 256, 0, stream>>>(
      ment, nullptr, fastT, KSEL, MENTD, KPAD, KPAD, fbP, nullptr,
      nullptr, 0, srcb, KPAD, KPAD, 0, nullptr, nullptr);
  k_mfma<<<dim3((KSEL+127)/128, (KSEL+127)/128), 256, 0, stream>>>(
      srcb, nullptr, ment, KSEL, KSEL, KPAD, KPAD, nullptr, mscore,
      fastm, KSEL, nullptr, 0, 0, MF_MASK, nullptr, nullptr);
  k_f3<<<(KSEL+3)/4, 256, 0, stream>>>(fastm, top_fast, antes);

  k_dsmall<<<18, 256, 0, stream>>>(ss_w1, ss_b1, spk_e, gen_e, dist_e, genre_id, comb);

  const u16* mcur = ment;
  for (int iter = 0; iter < 2; ++iter){
    k_mfma<<<dim3(8, (KSEL+127)/128), 256, 0, stream>>>(
        mcur, nullptr, ss1abT, KSEL, 1024, KPAD, KPAD, nullptr, nullptr,
        A_meb, 1024, nullptr, 0, 0, 0, nullptr, nullptr);
    k_d1_mfma<<<dim3(2, (NPAIR + 127)/128), 256, 0, stream>>>(
        NPAIR, mcur, antes, mspk, sspT, A_meb, comb, bufH1);
    k_mfma_rowdot<<<(NPAIR + 127)/128, 256, 0, stream>>>(bufH1, ss2T, NPAIR, ss_b2, ss_w3, ss_b3,
                                                         top_fast, ante_sc);
    if (iter == 0){
      k_d4a<<<KSEL, 256, 0, stream>>>(ante_sc, antes, mcur, att_bf);
      k_mfma<<<dim3((MENTD+127)/128, (KSEL+127)/128), 256, 0, stream>>>(
          ment, att_bf, gateTall, KSEL, MENTD, 2*KPAD, KPAD, gbP, nullptr,
          nullptr, 0, mentB, KPAD, KPAD, MF_GATE, att_bf, ment);
      mcur = mentB;
    }
  }

  k_out<<<(KSEL*41 + 255)/256, 256, 0, stream>>>(ante_sc, out);
}

// Round 12
// 1124.858 us; speedup vs baseline: 1.0274x; 1.0274x over previous
//
#include <hip/hip_runtime.h>
#include <math.h>

#define T_LEN 4096
#define FLATD 512
#define HDD 256
#define FEATD 20
#define NCAND 30000
#define HIDD 512
#define KSEL 1638
#define CANT 40
#define MENTD 1300
#define KPAD 1344
#define NPAIR (KSEL*CANT)
#define NEG_INF (-__builtin_inff())

#define MF_RELU 1
#define MF_MASK 4
#define MF_GATE 8

typedef unsigned short u16;
typedef __attribute__((ext_vector_type(8))) short bf16x8;
typedef __attribute__((ext_vector_type(4))) float f32x4;

__device__ __forceinline__ unsigned ordf(float f){
  unsigned u = __float_as_uint(f);
  return (u & 0x80000000u) ? ~u : (u | 0x80000000u);
}
__device__ __forceinline__ float unordf(unsigned u){
  return __uint_as_float((u & 0x80000000u) ? (u ^ 0x80000000u) : ~u);
}
__device__ __forceinline__ float bf2f(u16 h){ return __uint_as_float(((unsigned)h) << 16); }
__device__ __forceinline__ u16 f2bf(float f){
  unsigned u = __float_as_uint(f);
  u += 0x7fffu + ((u >> 16) & 1u);
  return (u16)(u >> 16);
}
__device__ __forceinline__ unsigned pkmul(unsigned a, unsigned b){
  float a0 = __uint_as_float(a << 16), a1 = __uint_as_float(a & 0xffff0000u);
  float b0 = __uint_as_float(b << 16), b1 = __uint_as_float(b & 0xffff0000u);
  float p0 = a0*b0, p1 = a1*b1;
  unsigned r;
  asm("v_cvt_pk_bf16_f32 %0, %1, %2" : "=v"(r) : "v"(p0), "v"(p1));
  return r;
}
// permuted feature layout [start512|end512|hemb256|wemb20|pad44] -> original source row
__device__ __forceinline__ int featsrc(int k){
  if (k < 1024) return k;
  if (k < 1280) return k + 20;
  if (k < 1300) return k - 256;
  return -1;
}
// BK=64 LDS: [rows][64] bf16. Stored slot s of row r holds source slot s^(r&7).
__device__ __forceinline__ int bsrc64(int S){
  return (((S & 7) ^ ((S >> 3) & 7)) << 3);
}
__device__ __forceinline__ int brd64(int row, int h, int k8){
  return row*64 + (((((h << 2) | k8)) ^ (row & 7)) << 3);
}
__device__ __forceinline__ void gload16(const u16* g, u16* l){
  __builtin_amdgcn_global_load_lds((const __attribute__((address_space(1))) void*)(g),
                                   (__attribute__((address_space(3))) void*)(l), 16, 0, 0);
}

// ---------------- prep: flat->bf16, padded wemb(20x64), permuted biases, selws zero ----------------
__global__ __launch_bounds__(256) void k_prep(const float* __restrict__ flat,
    const float* __restrict__ wemb, const float* __restrict__ fast_b, const float* __restrict__ gate_b,
    u16* __restrict__ flatbf, u16* __restrict__ wembP, float* __restrict__ fbP, float* __restrict__ gbP,
    unsigned* __restrict__ selws)
{
  int i = blockIdx.x*256 + threadIdx.x;
  if (i < T_LEN*FLATD) flatbf[i] = f2bf(flat[i]);
  if (i < 20*64) wembP[i] = ((i & 63) < 20) ? f2bf(wemb[(i >> 6)*FEATD + (i & 63)]) : (u16)0;
  if (i < KPAD){
    int s = featsrc(i);
    fbP[i] = (s >= 0) ? fast_b[s] : 0.f;
    gbP[i] = (s >= 0) ? gate_b[s] : 0.f;
  }
  if (i < 6156) selws[i] = 0;
}

// ---------------- head scores ----------------
__global__ __launch_bounds__(256) void k_head(const float* __restrict__ flat,
    const float* __restrict__ w, const float* __restrict__ b, float* __restrict__ hs)
{
  int lane = threadIdx.x & 63, wid = threadIdx.x >> 6;
  int row = blockIdx.x*4 + wid;
  if (row >= T_LEN) return;
  const float* x = flat + (size_t)row*FLATD;
  float s = 0.f;
  for (int j = lane; j < FLATD; j += 64) s += x[j]*w[j];
  #pragma unroll
  for (int o = 32; o; o >>= 1) s += __shfl_down(s, o, 64);
  if (lane == 0) hs[row] = s + b[0];
}

// ------------- per-candidate softmax head embedding -> bf16 (wave per candidate) -------------
__global__ __launch_bounds__(256) void k_cand(const float* __restrict__ hs,
    const float* __restrict__ hdoc, const int* __restrict__ starts, const int* __restrict__ ends,
    u16* __restrict__ hemb)
{
  int wid = threadIdx.x >> 6, lane = threadIdx.x & 63;
  int n = blockIdx.x*4 + wid;
  if (n >= NCAND) return;
  int s = starts[n], e = ends[n];
  int width = e - s + 1;
  float g[20];
  #pragma unroll
  for (int w2 = 0; w2 < 20; ++w2) g[w2] = (w2 < width) ? hs[min(s + w2, T_LEN-1)] : NEG_INF;
  float m = NEG_INF;
  #pragma unroll
  for (int w2 = 0; w2 < 20; ++w2) m = fmaxf(m, g[w2]);
  float sum = 0.f;
  #pragma unroll
  for (int w2 = 0; w2 < 20; ++w2){ g[w2] = expf(g[w2] - m); sum += g[w2]; }
  float inv = 1.f/sum;
  #pragma unroll
  for (int di = 0; di < 4; ++di){
    int d = lane + di*64;
    float acc = 0.f;
    #pragma unroll
    for (int w2 = 0; w2 < 20; ++w2)
      acc += g[w2]*hdoc[(size_t)min(s + w2, T_LEN-1)*HDD + d];
    hemb[(size_t)n*HDD + d] = f2bf(acc*inv);
  }
}

// ------------- batched weight transposes with feature permutation -------------
__global__ __launch_bounds__(256) void k_transall(const float* __restrict__ ms_w1,
    const float* __restrict__ ms_w2, const float* __restrict__ fast_w,
    const float* __restrict__ ss_w1, const float* __restrict__ ss_w2,
    const float* __restrict__ gate_w,
    u16* ms1T, u16* ms2T, u16* fastT, u16* ss1abT, u16* sspT,
    u16* ss2T, u16* gateTall)
{
  const float* B; u16* D; int Kb, N, srcN, ldD, kperm, nperm;
  switch (blockIdx.z){
    case 0: B = ms_w1; D = ms1T; Kb = KPAD; N = HIDD; srcN = HIDD; ldD = KPAD; kperm = 1; nperm = 0; break;
    case 1: B = ms_w2; D = ms2T; Kb = HIDD; N = HIDD; srcN = HIDD; ldD = HIDD; kperm = 0; nperm = 0; break;
    case 2: B = fast_w; D = fastT; Kb = KPAD; N = MENTD; srcN = MENTD; ldD = KPAD; kperm = 1; nperm = 1; break;
    case 3: B = ss_w1; D = ss1abT; Kb = KPAD; N = HIDD; srcN = HIDD; ldD = KPAD; kperm = 1; nperm = 0; break;
    case 4: B = ss_w1 + (size_t)MENTD*HIDD; D = ss1abT + (size_t)512*KPAD; Kb = KPAD; N = HIDD; srcN = HIDD; ldD = KPAD; kperm = 1; nperm = 0; break;
    case 5: B = ss_w1 + (size_t)2*MENTD*HIDD; D = sspT; Kb = KPAD; N = HIDD; srcN = HIDD; ldD = KPAD; kperm = 1; nperm = 0; break;
    case 6: B = ss_w2; D = ss2T; Kb = HIDD; N = HIDD; srcN = HIDD; ldD = HIDD; kperm = 0; nperm = 0; break;
    case 7: B = gate_w; D = gateTall; Kb = KPAD; N = MENTD; srcN = MENTD; ldD = 2*KPAD; kperm = 1; nperm = 1; break;
    default: B = gate_w + (size_t)MENTD*MENTD; D = gateTall + KPAD; Kb = KPAD; N = MENTD; srcN = MENTD; ldD = 2*KPAD; kperm = 1; nperm = 1; break;
  }
  int k0 = blockIdx.x*32, n0 = blockIdx.y*32;
  if (k0 >= Kb || n0 >= N) return;
  __shared__ float t[32][33];
  int tx = threadIdx.x & 31, ty = threadIdx.x >> 5;
  for (int r = ty; r < 32; r += 8){
    int gk = k0 + r, gn = n0 + tx;
    int sk = kperm ? featsrc(gk) : ((gk < Kb) ? gk : -1);
    int sn = nperm ? ((gn < N) ? featsrc(gn) : -1) : ((gn < N) ? gn : -1);
    t[r][tx] = (sk >= 0 && sn >= 0) ? B[(size_t)sk*srcN + sn] : 0.f;
  }
  __syncthreads();
  for (int r = ty; r < 32; r += 8){
    int gn = n0 + r, gk = k0 + tx;
    if (gn < N && gk < Kb) D[(size_t)gn*ldD + gk] = f2bf(t[tx][r]);
  }
}

// ------- mention-scorer layer1: A rows built on the fly, BK=64, gload_lds -------
__global__ __launch_bounds__(256) void k_mfma_cand(
    const u16* __restrict__ flatbf, const u16* __restrict__ hemb, const u16* __restrict__ wembP,
    const int* __restrict__ starts, const int* __restrict__ ends,
    const u16* __restrict__ Bt, int M, const float* __restrict__ bias, u16* __restrict__ Cbf)
{
  __shared__ alignas(16) u16 As[8192];
  __shared__ alignas(16) u16 Bs[8192];
  int tid = threadIdx.x;
  int row0 = blockIdx.y*128, col0 = blockIdx.x*128;
  int lane = tid & 63, wid = tid >> 6;
  int wr = wid >> 1, wc = wid & 1;
  int l15 = lane & 15, l4 = lane >> 4;

  int sS[4], eS[4], nS[4], so[4];
  const u16* pb[4];
  #pragma unroll
  for (int i = 0; i < 4; ++i){
    int S = tid + (i << 8);
    int r = S >> 3;
    so[i] = bsrc64(S);
    int n = row0 + r; if (n >= M) n = M - 1;
    sS[i] = starts[n]; eS[i] = ends[n]; nS[i] = n;
    pb[i] = Bt + (size_t)(col0 + r)*KPAD + so[i];
  }

  f32x4 acc[4][4];
  #pragma unroll
  for (int m = 0; m < 4; ++m)
    #pragma unroll
    for (int n = 0; n < 4; ++n)
      #pragma unroll
      for (int q = 0; q < 4; ++q) acc[m][n][q] = 0.f;

  for (int kt = 0; kt < KPAD/64; ++kt){
    int k0 = kt << 6;
    #pragma unroll
    for (int i = 0; i < 4; ++i){
      int f = k0 + so[i];
      const u16* src = (f < 512) ? flatbf + (size_t)sS[i]*FLATD + f
                     : (f < 1024) ? flatbf + (size_t)eS[i]*FLATD + (f - 512)
                     : (f < 1280) ? hemb + (size_t)nS[i]*HDD + (f - 1024)
                     : wembP + (eS[i] - sS[i])*64 + (f - 1280);
      gload16(src, As + (tid + (i << 8))*8);
      gload16(pb[i] + k0, Bs + (tid + (i << 8))*8);
    }
    __syncthreads();
    #pragma unroll
    for (int h = 0; h < 2; ++h){
      bf16x8 af[4], bfr[4];
      #pragma unroll
      for (int m = 0; m < 4; ++m) af[m] = *(const bf16x8*)(As + brd64(wr*64 + m*16 + l15, h, l4));
      #pragma unroll
      for (int n = 0; n < 4; ++n) bfr[n] = *(const bf16x8*)(Bs + brd64(wc*64 + n*16 + l15, h, l4));
      #pragma unroll
      for (int m = 0; m < 4; ++m)
        #pragma unroll
        for (int n = 0; n < 4; ++n)
          acc[m][n] = __builtin_amdgcn_mfma_f32_16x16x32_bf16(af[m], bfr[n], acc[m][n], 0, 0, 0);
    }
    __syncthreads();
  }
  #pragma unroll
  for (int m = 0; m < 4; ++m){
    #pragma unroll
    for (int q = 0; q < 4; ++q){
      int grow = row0 + wr*64 + m*16 + l4*4 + q;
      if (grow >= M) continue;
      #pragma unroll
      for (int n = 0; n < 4; ++n){
        int gcol = col0 + wc*64 + n*16 + l15;
        float v = fmaxf(acc[m][n][q] + bias[gcol], 0.f);
        Cbf[(size_t)grow*HIDD + gcol] = f2bf(v);
      }
    }
  }
}

// ---------------- generic bf16 MFMA GEMM, BK=64 (global_load_lds staging) ----------------
__global__ __launch_bounds__(256) void k_mfma(const u16* __restrict__ A,
    const u16* __restrict__ A2, const u16* __restrict__ Bt, int M, int N, int Kp, int ldA,
    const float* __restrict__ bias, const float* __restrict__ msc,
    float* __restrict__ Cf, int ldf, u16* __restrict__ Cbf, int ldbf, int Nstore, int flags,
    const u16* __restrict__ g_att, const u16* __restrict__ g_mo)
{
  __shared__ alignas(16) u16 As[8192];
  __shared__ alignas(16) u16 Bs[8192];
  int tid = threadIdx.x;
  int row0 = blockIdx.y*128, col0 = blockIdx.x*128;
  if ((flags & MF_MASK) && col0 >= row0 + 128) return;
  int lane = tid & 63, wid = tid >> 6;
  int wr = wid >> 1, wc = wid & 1;
  int l15 = lane & 15, l4 = lane >> 4;

  const u16 *pa[4], *qa[4], *pb[4];
  int kt1 = A2 ? (ldA >> 6) : (Kp >> 6);
  int koff = kt1 << 6;
  #pragma unroll
  for (int i = 0; i < 4; ++i){
    int S = tid + (i << 8);
    int r = S >> 3;
    int soi = bsrc64(S);
    int ra = row0 + r; if (ra >= M) ra = M - 1;
    int cb = col0 + r; if (cb >= N) cb = N - 1;
    pa[i] = A + (size_t)ra*ldA + soi;
    qa[i] = A2 ? (A2 + (size_t)ra*ldA + soi - koff) : pa[i];
    pb[i] = Bt + (size_t)cb*Kp + soi;
  }

  f32x4 acc[4][4];
  #pragma unroll
  for (int m = 0; m < 4; ++m)
    #pragma unroll
    for (int n = 0; n < 4; ++n)
      #pragma unroll
      for (int q = 0; q < 4; ++q) acc[m][n][q] = 0.f;

  int nkt = Kp >> 6;
  for (int kt = 0; kt < nkt; ++kt){
    int k0 = kt << 6;
    #pragma unroll
    for (int i = 0; i < 4; ++i){
      const u16* a = (kt < kt1) ? pa[i] : qa[i];
      gload16(a + k0, As + (tid + (i << 8))*8);
      gload16(pb[i] + k0, Bs + (tid + (i << 8))*8);
    }
    __syncthreads();
    #pragma unroll
    for (int h = 0; h < 2; ++h){
      bf16x8 af[4], bfr[4];
      #pragma unroll
      for (int m = 0; m < 4; ++m) af[m] = *(const bf16x8*)(As + brd64(wr*64 + m*16 + l15, h, l4));
      #pragma unroll
      for (int n = 0; n < 4; ++n) bfr[n] = *(const bf16x8*)(Bs + brd64(wc*64 + n*16 + l15, h, l4));
      #pragma unroll
      for (int m = 0; m < 4; ++m)
        #pragma unroll
        for (int n = 0; n < 4; ++n)
          acc[m][n] = __builtin_amdgcn_mfma_f32_16x16x32_bf16(af[m], bfr[n], acc[m][n], 0, 0, 0);
    }
    __syncthreads();
  }
  #pragma unroll
  for (int m = 0; m < 4; ++m){
    #pragma unroll
    for (int q = 0; q < 4; ++q){
      int grow = row0 + wr*64 + m*16 + l4*4 + q;
      if (grow >= M) continue;
      #pragma unroll
      for (int n = 0; n < 4; ++n){
        int gcol = col0 + wc*64 + n*16 + l15;
        if (gcol < N){
          float v = acc[m][n][q];
          if (bias) v += bias[gcol];
          if (flags & MF_MASK){ v += msc[grow] + msc[gcol]; if (gcol >= grow) v = NEG_INF; }
          if (flags & MF_RELU) v = fmaxf(v, 0.f);
          if (flags & MF_GATE){
            float f = 1.f/(1.f + expf(-v));
            float res = f*bf2f(g_att[(size_t)grow*ldbf + gcol])
                      + (1.f - f)*bf2f(g_mo[(size_t)grow*ldbf + gcol]);
            Cbf[(size_t)grow*ldbf + gcol] = f2bf(res);
          } else {
            if (Cf)  Cf[(size_t)grow*ldf + gcol] = v;
            if (Cbf) Cbf[(size_t)grow*ldbf + gcol] = f2bf(v);
          }
        } else if (Cbf && gcol < Nstore){
          Cbf[(size_t)grow*ldbf + gcol] = 0;
        }
      }
    }
  }
}

// ---- fused layer2 + w3 dot, full row per block, BK=64 (R8-proven) ----
__global__ __launch_bounds__(256) void k_mfma_rowdot(const u16* __restrict__ A,
    const u16* __restrict__ Bt, int M, const float* __restrict__ b2,
    const float* __restrict__ w3, const float* __restrict__ b3,
    const float* __restrict__ add, float* __restrict__ out)
{
  __shared__ alignas(16) u16 As[8192];
  __shared__ alignas(16) u16 Bs[8192];
  __shared__ float rsum[128][2];
  int tid = threadIdx.x;
  int row0 = blockIdx.x*128;
  int lane = tid & 63, wid = tid >> 6;
  int wr = wid >> 1, wc = wid & 1;
  int l15 = lane & 15, l4 = lane >> 4;

  const u16* pa[4]; int so[4], rr[4];
  #pragma unroll
  for (int i = 0; i < 4; ++i){
    int S = tid + (i << 8);
    int r = S >> 3;
    so[i] = bsrc64(S); rr[i] = r;
    int ra = row0 + r; if (ra >= M) ra = M - 1;
    pa[i] = A + (size_t)ra*HIDD + so[i];
  }

  float rd[4][4] = {};
  for (int p = 0; p < 4; ++p){
    int col0 = p*128;
    f32x4 acc[4][4];
    #pragma unroll
    for (int m = 0; m < 4; ++m)
      #pragma unroll
      for (int n = 0; n < 4; ++n)
        #pragma unroll
        for (int q = 0; q < 4; ++q) acc[m][n][q] = 0.f;
    for (int kt = 0; kt < HIDD/64; ++kt){
      int k0 = kt << 6;
      #pragma unroll
      for (int i = 0; i < 4; ++i){
        gload16(pa[i] + k0, As + (tid + (i << 8))*8);
        gload16(Bt + (size_t)(col0 + rr[i])*HIDD + so[i] + k0, Bs + (tid + (i << 8))*8);
      }
      __syncthreads();
      #pragma unroll
      for (int h = 0; h < 2; ++h){
        bf16x8 af[4], bfr[4];
        #pragma unroll
        for (int m = 0; m < 4; ++m) af[m] = *(const bf16x8*)(As + brd64(wr*64 + m*16 + l15, h, l4));
        #pragma unroll
        for (int n = 0; n < 4; ++n) bfr[n] = *(const bf16x8*)(Bs + brd64(wc*64 + n*16 + l15, h, l4));
        #pragma unroll
        for (int m = 0; m < 4; ++m)
          #pragma unroll
          for (int n = 0; n < 4; ++n)
            acc[m][n] = __builtin_amdgcn_mfma_f32_16x16x32_bf16(af[m], bfr[n], acc[m][n], 0, 0, 0);
      }
      __syncthreads();
    }
    #pragma unroll
    for (int n = 0; n < 4; ++n){
      int gcol = col0 + wc*64 + n*16 + l15;
      float bb = b2[gcol], ww = w3[gcol];
      #pragma unroll
      for (int m = 0; m < 4; ++m)
        #pragma unroll
        for (int q = 0; q < 4; ++q){
          float v = fmaxf(acc[m][n][q] + bb, 0.f);
          rd[m][q] = fmaf(v, ww, rd[m][q]);
        }
    }
  }
  #pragma unroll
  for (int m = 0; m < 4; ++m)
    #pragma unroll
    for (int q = 0; q < 4; ++q){
      float s = rd[m][q];
      s += __shfl_xor(s, 1, 64); s += __shfl_xor(s, 2, 64);
      s += __shfl_xor(s, 4, 64); s += __shfl_xor(s, 8, 64);
      if (l15 == 0) rsum[wr*64 + m*16 + l4*4 + q][wc] = s;
    }
  __syncthreads();
  if (tid < 128){
    int gr = row0 + tid;
    if (gr < M){
      float v = rsum[tid][0] + rsum[tid][1] + b3[0];
      if (add) v += add[gr];
      out[gr] = v;
    }
  }
}

// ------- pair layer1 MFMA: 128x256 tile, BK=64, staged on-the-fly product A (R8-proven) -------
__global__ __launch_bounds__(256, 2) void k_d1_mfma(int Mc,
    const u16* __restrict__ ment, const int* __restrict__ antes, const int* __restrict__ mspk,
    const u16* __restrict__ Bt, const float* __restrict__ A_meb,
    const float* __restrict__ comb, u16* __restrict__ H1)
{
  __shared__ alignas(16) u16 As[8192];    // 128 rows x 64
  __shared__ alignas(16) u16 Bs[16384];   // 256 cols x 64
  __shared__ int ri[128], rj[128], rcomb[128];
  int tid = threadIdx.x;
  int row0 = blockIdx.y*128;
  int col0 = blockIdx.x*256;
  if (tid < 128){
    int r = row0 + tid;
    int p = (r < Mc ? r : 0);
    int i = p / CANT;
    int j = antes[p];
    ri[tid] = i; rj[tid] = j;
    int same = (mspk[i] == mspk[j]) ? 1 : 0;
    int d = i - j; d = d < 0 ? 0 : (d > 64 ? 64 : d);
    int bin = (d <= 4) ? d : (d <= 8 ? 5 : (d <= 16 ? 6 : (d <= 32 ? 7 : 8)));
    rcomb[tid] = same*9 + bin;
  }
  __syncthreads();
  int lane = tid & 63, wid = tid >> 6;
  int wr = wid >> 1, wc = wid & 1;
  int l15 = lane & 15, l4 = lane >> 4;

  const u16 *pi[4], *pj[4];
  #pragma unroll
  for (int i = 0; i < 4; ++i){
    int S = tid + (i << 8);
    int r = S >> 3;
    int soi = bsrc64(S);
    pi[i] = ment + (size_t)ri[r]*KPAD + soi;
    pj[i] = ment + (size_t)rj[r]*KPAD + soi;
  }
  int bo[8];
  #pragma unroll
  for (int i = 0; i < 8; ++i){
    int S = tid + (i << 8);
    int r = S >> 3;
    bo[i] = (col0 + r)*KPAD + bsrc64(S);
  }

  f32x4 acc[4][8];
  #pragma unroll
  for (int m = 0; m < 4; ++m)
    #pragma unroll
    for (int n = 0; n < 8; ++n)
      #pragma unroll
      for (int q = 0; q < 4; ++q) acc[m][n][q] = 0.f;

  int nkt = KPAD >> 6;
  for (int kt = 0; kt < nkt; ++kt){
    int k0 = kt << 6;
    #pragma unroll
    for (int i = 0; i < 8; ++i)
      gload16(Bt + bo[i] + k0, Bs + (tid + (i << 8))*8);
    #pragma unroll
    for (int i = 0; i < 4; ++i){
      uint4 va = *(const uint4*)(pi[i] + k0);
      uint4 vb = *(const uint4*)(pj[i] + k0);
      uint4 vo;
      vo.x = pkmul(va.x, vb.x); vo.y = pkmul(va.y, vb.y);
      vo.z = pkmul(va.z, vb.z); vo.w = pkmul(va.w, vb.w);
      *(uint4*)(As + (tid + (i << 8))*8) = vo;
    }
    __syncthreads();
    #pragma unroll
    for (int h = 0; h < 2; ++h){
      bf16x8 af[4];
      #pragma unroll
      for (int m = 0; m < 4; ++m) af[m] = *(const bf16x8*)(As + brd64(wr*64 + m*16 + l15, h, l4));
      #pragma unroll
      for (int n = 0; n < 8; ++n){
        bf16x8 bfr = *(const bf16x8*)(Bs + brd64(wc*128 + n*16 + l15, h, l4));
        #pragma unroll
        for (int m = 0; m < 4; ++m)
          acc[m][n] = __builtin_amdgcn_mfma_f32_16x16x32_bf16(af[m], bfr, acc[m][n], 0, 0, 0);
      }
    }
    __syncthreads();
  }
  #pragma unroll
  for (int m = 0; m < 4; ++m){
    #pragma unroll
    for (int q = 0; q < 4; ++q){
      int rl = wr*64 + m*16 + l4*4 + q;
      int grow = row0 + rl;
      if (grow >= Mc) continue;
      const float* me = A_meb + (size_t)ri[rl]*1024;
      const float* an = A_meb + (size_t)rj[rl]*1024 + 512;
      const float* cb = comb + (size_t)rcomb[rl]*HIDD;
      #pragma unroll
      for (int n = 0; n < 8; ++n){
        int gcol = col0 + wc*128 + n*16 + l15;
        float v = acc[m][n][q] + me[gcol] + an[gcol] + cb[gcol];
        H1[(size_t)grow*HIDD + gcol] = f2bf(fmaxf(v, 0.f));
      }
    }
  }
}

// ================= top-K selection pipeline (multi-kernel, multi-CU; R8-proven) =================
__global__ __launch_bounds__(256) void k_hist(const float* __restrict__ scores,
    unsigned* __restrict__ selws, int pass)
{
  int n = blockIdx.x*256 + threadIdx.x;
  if (n >= NCAND) return;
  unsigned u = ordf(scores[n]);
  const unsigned* meta = selws + 6144;
  if (pass == 0) atomicAdd(&selws[u >> 21], 1u);
  else if (pass == 1){ if ((u >> 21) == meta[0]) atomicAdd(&selws[2048 + ((u >> 10) & 0x7FFu)], 1u); }
  else { if ((u >> 10) == meta[2]) atomicAdd(&selws[4096 + (u & 0x3FFu)], 1u); }
}
__global__ __launch_bounds__(1024) void k_thresh(unsigned* __restrict__ selws, int mode){
  __shared__ unsigned a[2048], b[2048];
  int tid = threadIdx.x;
  unsigned* meta = selws + 6144;
  const unsigned* gbin = selws + (mode == 0 ? 0 : (mode == 1 ? 2048 : 4096));
  unsigned target = (mode == 0) ? (unsigned)KSEL : meta[mode == 1 ? 1 : 3];
  a[tid] = gbin[tid]; a[tid + 1024] = gbin[tid + 1024];
  unsigned *src = a, *dst = b;
  for (int step = 1; step < 2048; step <<= 1){
    __syncthreads();
    for (int i = tid; i < 2048; i += 1024)
      dst[i] = src[i] + ((i + step < 2048) ? src[i + step] : 0u);
    unsigned* t2 = src; src = dst; dst = t2;
  }
  __syncthreads();
  for (int i = tid; i < 2048; i += 1024){
    unsigned si = src[i], sn = (i < 2047) ? src[i+1] : 0u;
    if (si >= target && sn < target){
      if (mode == 0){ meta[0] = (unsigned)i; meta[1] = target - sn; }
      else if (mode == 1){ meta[2] = (meta[0] << 11) | (unsigned)i; meta[3] = target - sn; }
      else { meta[4] = (meta[2] << 10) | (unsigned)i; meta[5] = target - sn; }
    }
  }
}
__global__ __launch_bounds__(256) void k_compact(const float* __restrict__ scores,
    unsigned* __restrict__ selws, int* __restrict__ g_sel, unsigned* __restrict__ g_eq)
{
  int n = blockIdx.x*256 + threadIdx.x;
  if (n >= NCAND) return;
  unsigned kth = selws[6144 + 4];
  unsigned* cnt = selws + 6152;
  unsigned u = ordf(scores[n]);
  if (u > kth){ unsigned p = atomicAdd(&cnt[0], 1u); g_sel[p] = n; }
  else if (u == kth){ unsigned p = atomicAdd(&cnt[1], 1u); if (p < 1024) g_eq[p] = (unsigned)n; }
}
__global__ __launch_bounds__(1024) void k_eqrank(unsigned* __restrict__ selws,
    const unsigned* __restrict__ g_eq, int* __restrict__ g_sel)
{
  __shared__ unsigned eq[1024];
  int tid = threadIdx.x;
  unsigned neq = selws[6152 + 1]; if (neq > 1024u) neq = 1024u;
  unsigned E = selws[6144 + 5];
  unsigned G = selws[6152 + 0];
  eq[tid] = (tid < (int)neq) ? g_eq[tid] : 0xFFFFFFFFu;
  __syncthreads();
  if (tid < (int)neq){
    unsigned mine = eq[tid]; unsigned r = 0;
    for (unsigned j = 0; j < neq; ++j) r += (eq[j] < mine) ? 1u : 0u;
    if (r < E) g_sel[G + r] = (int)mine;
  }
}
__global__ __launch_bounds__(256) void k_rank1(const float* __restrict__ scores,
    const int* __restrict__ g_sel, int* __restrict__ ranked)
{
  __shared__ unsigned long long key[KSEL];
  int tid = threadIdx.x;
  for (int t = tid; t < KSEL; t += 256){
    int n = g_sel[t];
    key[t] = ((unsigned long long)(~ordf(scores[n])) << 32) | (unsigned)n;
  }
  __syncthreads();
  int t = blockIdx.x*256 + tid;
  if (t >= KSEL) return;
  unsigned long long mine = key[t];
  int r = 0;
  #pragma unroll 16
  for (int j = 0; j < KSEL; ++j) r += (key[j] < mine) ? 1 : 0;
  ranked[r] = (int)(mine & 0xFFFFFFFFu);
}
__global__ __launch_bounds__(256) void k_rank2(const int* __restrict__ ranked,
    const int* __restrict__ starts, const int* __restrict__ ends, int* __restrict__ top_idx)
{
  __shared__ unsigned long long key[KSEL];
  int tid = threadIdx.x;
  int elast = ends[NCAND-1];
  for (int t = tid; t < KSEL; t += 256){
    int n = ranked[t];
    unsigned mp = (unsigned)(starts[n]*elast + ends[n]);
    key[t] = ((unsigned long long)mp << 11) | (unsigned)t;
  }
  __syncthreads();
  int t = blockIdx.x*256 + tid;
  if (t >= KSEL) return;
  unsigned long long mine = key[t];
  int r = 0;
  #pragma unroll 16
  for (int j = 0; j < KSEL; ++j) r += (key[j] < mine) ? 1 : 0;
  top_idx[r] = ranked[t];
}

// ---------------- gather mention rows -> bf16 [KSEL][KPAD], permuted layout ----------------
__global__ __launch_bounds__(256) void k_gather(const int* __restrict__ top_idx,
    const u16* __restrict__ flatbf, const u16* __restrict__ hemb, const u16* __restrict__ wembP,
    const int* __restrict__ starts, const int* __restrict__ ends,
    const float* __restrict__ cscores, const int* __restrict__ spk_ids,
    u16* __restrict__ ment, float* __restrict__ mscore, int* __restrict__ mspk)
{
  int k = blockIdx.x; int n = top_idx[k];
  int s = starts[n], e = ends[n];
  int v = threadIdx.x;
  if (v < KPAD/8){
    int f0 = v*8;
    const u16* src = (f0 < 512) ? flatbf + (size_t)s*FLATD + f0
                   : (f0 < 1024) ? flatbf + (size_t)e*FLATD + (f0 - 512)
                   : (f0 < 1280) ? hemb + (size_t)n*HDD + (f0 - 1024)
                   : wembP + (e - s)*64 + (f0 - 1280);
    *(uint4*)(ment + (size_t)k*KPAD + f0) = *(const uint4*)src;
  }
  if (threadIdx.x == 0){ mscore[k] = cscores[n]; mspk[k] = spk_ids[s]; }
}

// ---------------- per-row top-40, wave-per-row, register keys ----------------
__global__ __launch_bounds__(256) void k_f3(const float* __restrict__ fast,
    float* __restrict__ top_fast, int* __restrict__ antes)
{
  int wid = threadIdx.x >> 6, lane = threadIdx.x & 63;
  int i = blockIdx.x*4 + wid;
  if (i >= KSEL) return;
  const float* row = fast + (size_t)i*KSEL;
  unsigned long long key[26];
  #pragma unroll
  for (int t = 0; t < 26; ++t){
    int j = lane + (t << 6);
    unsigned long long k2 = 0ULL;
    if (j < i) k2 = ((unsigned long long)ordf(row[j]) << 32) | (unsigned)(0xFFFFFFFFu - (unsigned)j);
    key[t] = k2;
  }
  for (int c = 0; c < CANT; ++c){
    unsigned long long m = 0ULL;
    #pragma unroll
    for (int t = 0; t < 26; ++t) if (key[t] > m) m = key[t];
    #pragma unroll
    for (int o = 32; o; o >>= 1){
      unsigned long long v = __shfl_xor(m, o, 64);
      if (v > m) m = v;
    }
    if (m){
      #pragma unroll
      for (int t = 0; t < 26; ++t) if (key[t] == m) key[t] = 0ULL;
    }
    if (lane == 0){
      if (m){
        top_fast[(size_t)i*CANT + c] = unordf((unsigned)(m >> 32));
        antes[(size_t)i*CANT + c]    = (int)(0xFFFFFFFFu - (unsigned)(m & 0xFFFFFFFFu));
      } else {
        top_fast[(size_t)i*CANT + c] = NEG_INF;
        antes[(size_t)i*CANT + c]    = c;
      }
    }
  }
}

// ------- comb[same*9+bin][512]: (spk+genre+dist) rows through ss_w1 + b1, pre-summed -------
__global__ __launch_bounds__(256) void k_dsmall(const float* __restrict__ ss_w1,
    const float* __restrict__ ss_b1, const float* __restrict__ spk_emb,
    const float* __restrict__ gen_emb, const float* __restrict__ dist_emb,
    const int* __restrict__ genre_id, float* __restrict__ comb)
{
  int r = blockIdx.x;             // 0..17
  int same = r / 9, bin = r % 9;
  const float* es = spk_emb + same*FEATD;
  const float* eg = gen_emb + genre_id[0]*FEATD;
  const float* ed = dist_emb + bin*FEATD;
  for (int h = threadIdx.x; h < HIDD; h += 256){
    float acc = ss_b1[h];
    const float* ws_ = ss_w1 + (size_t)3900*HIDD + h;
    const float* wg  = ss_w1 + (size_t)3920*HIDD + h;
    const float* wd  = ss_w1 + (size_t)3940*HIDD + h;
    for (int f = 0; f < FEATD; ++f){
      acc += es[f]*ws_[(size_t)f*HIDD];
      acc += eg[f]*wg[(size_t)f*HIDD];
      acc += ed[f]*wd[(size_t)f*HIDD];
    }
    comb[(size_t)r*HIDD + h] = acc;
  }
}

// ---------------- softmax over [0, ante_scores] + attended -> bf16 (vectorized) ----------------
__global__ __launch_bounds__(256) void k_d4a(const float* __restrict__ ante_sc,
    const int* __restrict__ antes, const u16* __restrict__ ment, u16* __restrict__ att_bf)
{
  int i = blockIdx.x;
  __shared__ float w[CANT+1];
  __shared__ int aj[CANT];
  if (threadIdx.x == 0){
    float s[CANT]; float m = 0.f;
    #pragma unroll
    for (int c = 0; c < CANT; ++c){ s[c] = ante_sc[i*CANT + c]; m = fmaxf(m, s[c]); }
    float e0 = expf(0.f - m);
    float sum = e0;
    float ex[CANT];
    #pragma unroll
    for (int c = 0; c < CANT; ++c){ ex[c] = expf(s[c] - m); sum += ex[c]; }
    float inv = 1.f/sum;
    w[0] = e0*inv;
    #pragma unroll
    for (int c = 0; c < CANT; ++c) w[c+1] = ex[c]*inv;
  }
  if (threadIdx.x < CANT) aj[threadIdx.x] = antes[i*CANT + threadIdx.x];
  __syncthreads();
  int v = threadIdx.x;
  if (v >= KPAD/8) return;
  int d0 = v*8;
  float r[8] = {};
  {
    uint4 x = *(const uint4*)(ment + (size_t)i*KPAD + d0);
    float w0 = w[0];
    const unsigned* px = (const unsigned*)&x;
    #pragma unroll
    for (int h = 0; h < 4; ++h){
      r[2*h]   = w0*__uint_as_float(px[h] << 16);
      r[2*h+1] = w0*__uint_as_float(px[h] & 0xffff0000u);
    }
  }
  for (int c = 0; c < CANT; ++c){
    uint4 x = *(const uint4*)(ment + (size_t)aj[c]*KPAD + d0);
    float wc_ = w[c+1];
    const unsigned* px = (const unsigned*)&x;
    #pragma unroll
    for (int h = 0; h < 4; ++h){
      r[2*h]   = fmaf(wc_, __uint_as_float(px[h] << 16), r[2*h]);
      r[2*h+1] = fmaf(wc_, __uint_as_float(px[h] & 0xffff0000u), r[2*h+1]);
    }
  }
  u16 o[8];
  #pragma unroll
  for (int h = 0; h < 8; ++h) o[h] = f2bf(r[h]);
  *(uint4*)(att_bf + (size_t)i*KPAD + d0) = *(const uint4*)o;
}

// ---------------- final output (sanitize non-finite) ----------------
__global__ __launch_bounds__(256) void k_out(const float* __restrict__ ante_sc, float* __restrict__ out){
  int idx = blockIdx.x*256 + threadIdx.x;
  if (idx >= KSEL*41) return;
  int i = idx / 41, c = idx % 41;
  float v = (c == 0) ? 0.f : ante_sc[i*CANT + (c-1)];
  if (!isfinite(v)) v = -3.0e38f;
  out[idx] = v;
}

__global__ void k_zero(float* out, int n){
  int i = blockIdx.x*256 + threadIdx.x;
  if (i < n) out[i] = 0.f;
}

extern "C" void kernel_launch(void* const* d_in, const int* in_sizes, int n_in,
                              void* d_out, int out_size, void* d_ws, size_t ws_size,
                              hipStream_t stream)
{
  const float* flat   = (const float*)d_in[0];
  const float* hdoc   = (const float*)d_in[1];
  const float* w_head = (const float*)d_in[2];
  const float* b_head = (const float*)d_in[3];
  const float* wemb   = (const float*)d_in[4];
  const float* ms_w1  = (const float*)d_in[5];
  const float* ms_b1  = (const float*)d_in[6];
  const float* ms_w2  = (const float*)d_in[7];
  const float* ms_b2  = (const float*)d_in[8];
  const float* ms_w3  = (const float*)d_in[9];
  const float* ms_b3  = (const float*)d_in[10];
  const float* fast_w = (const float*)d_in[11];
  const float* fast_b = (const float*)d_in[12];
  const float* ss_w1  = (const float*)d_in[13];
  const float* ss_b1  = (const float*)d_in[14];
  const float* ss_w2  = (const float*)d_in[15];
  const float* ss_b2  = (const float*)d_in[16];
  const float* ss_w3  = (const float*)d_in[17];
  const float* ss_b3  = (const float*)d_in[18];
  const float* gate_w = (const float*)d_in[19];
  const float* gate_b = (const float*)d_in[20];
  const float* spk_e  = (const float*)d_in[21];
  const float* gen_e  = (const float*)d_in[22];
  const float* dist_e = (const float*)d_in[23];
  const int* starts   = (const int*)d_in[24];
  const int* ends     = (const int*)d_in[25];
  const int* spk_ids  = (const int*)d_in[26];
  const int* genre_id = (const int*)d_in[27];
  float* out = (float*)d_out;

  size_t off = 0;
  char* base = (char*)d_ws;
  auto alloc = [&](size_t nbytes) -> void* {
    void* p = (void*)(base + off);
    off += ((nbytes + 255)/256)*256;
    return p;
  };
  float* head_sc = (float*)alloc((size_t)T_LEN*4);
  u16*   flatbf  = (u16*)alloc((size_t)T_LEN*FLATD*2);
  u16*   wembP   = (u16*)alloc((size_t)20*64*2);
  float* fbP     = (float*)alloc((size_t)KPAD*4);
  float* gbP     = (float*)alloc((size_t)KPAD*4);
  u16*   hemb    = (u16*)alloc((size_t)NCAND*HDD*2);
  float* cscores = (float*)alloc((size_t)NCAND*4);
  int*   top_idx = (int*)alloc(2048*4);
  unsigned* selws= (unsigned*)alloc(6160*4);
  int*   g_sel   = (int*)alloc((size_t)KSEL*4);
  unsigned* g_eq = (unsigned*)alloc(1024*4);
  int*   g_rank  = (int*)alloc((size_t)KSEL*4);
  u16*   ms1T    = (u16*)alloc((size_t)HIDD*KPAD*2);
  u16*   ms2T    = (u16*)alloc((size_t)HIDD*HIDD*2);
  u16*   fastT   = (u16*)alloc((size_t)MENTD*KPAD*2);
  u16*   ss1abT  = (u16*)alloc((size_t)1024*KPAD*2);
  u16*   sspT    = (u16*)alloc((size_t)HIDD*KPAD*2);
  u16*   ss2T    = (u16*)alloc((size_t)HIDD*HIDD*2);
  u16*   gateTall= (u16*)alloc((size_t)MENTD*2*KPAD*2);
  u16*   ment    = (u16*)alloc((size_t)KSEL*KPAD*2);
  u16*   mentB   = (u16*)alloc((size_t)KSEL*KPAD*2);
  u16*   srcb    = (u16*)alloc((size_t)KSEL*KPAD*2);
  float* mscore  = (float*)alloc((size_t)KSEL*4);
  int*   mspk    = (int*)alloc((size_t)KSEL*4);
  float* fastm   = (float*)alloc((size_t)KSEL*KSEL*4);
  float* top_fast= (float*)alloc((size_t)NPAIR*4);
  int*   antes   = (int*)alloc((size_t)NPAIR*4);
  float* ante_sc = (float*)alloc((size_t)NPAIR*4);
  float* A_meb   = (float*)alloc((size_t)KSEL*1024*4);
  float* comb    = (float*)alloc((size_t)18*HIDD*4);
  u16*   att_bf  = (u16*)alloc((size_t)KSEL*KPAD*2);
  u16*   bufH1   = (u16*)alloc((size_t)NPAIR*HIDD*2);

  if (ws_size < off){
    k_zero<<<(KSEL*41 + 255)/256, 256, 0, stream>>>(out, KSEL*41);
    return;
  }

  k_prep<<<(T_LEN*FLATD + 255)/256, 256, 0, stream>>>(flat, wemb, fast_b, gate_b,
                                                      flatbf, wembP, fbP, gbP, selws);
  k_transall<<<dim3(KPAD/32, 41, 9), 256, 0, stream>>>(ms_w1, ms_w2, fast_w, ss_w1, ss_w2, gate_w,
      ms1T, ms2T, fastT, ss1abT, sspT, ss2T, gateTall);

  k_head<<<T_LEN/4, 256, 0, stream>>>(flat, w_head, b_head, head_sc);
  k_cand<<<NCAND/4, 256, 0, stream>>>(head_sc, hdoc, starts, ends, hemb);

  // mention scorer (single pass over 30000 rows)
  k_mfma_cand<<<dim3(HIDD/128, (NCAND + 127)/128), 256, 0, stream>>>(
      flatbf, hemb, wembP, starts, ends, ms1T, NCAND, ms_b1, bufH1);
  k_mfma_rowdot<<<(NCAND + 127)/128, 256, 0, stream>>>(bufH1, ms2T, NCAND, ms_b2, ms_w3, ms_b3,
                                                       nullptr, cscores);

  // top-K selection pipeline
  k_hist<<<(NCAND + 255)/256, 256, 0, stream>>>(cscores, selws, 0);
  k_thresh<<<1, 1024, 0, stream>>>(selws, 0);
  k_hist<<<(NCAND + 255)/256, 256, 0, stream>>>(cscores, selws, 1);
  k_thresh<<<1, 1024, 0, stream>>>(selws, 1);
  k_hist<<<(NCAND + 255)/256, 256, 0, stream>>>(cscores, selws, 2);
  k_thresh<<<1, 1024, 0, stream>>>(selws, 2);
  k_compact<<<(NCAND + 255)/256, 256, 0, stream>>>(cscores, selws, g_sel, g_eq);
  k_eqrank<<<1, 1024, 0, stream>>>(selws, g_eq, g_sel);
  k_rank1<<<(KSEL + 255)/256, 256, 0, stream>>>(cscores, g_sel, g_rank);
  k_rank2<<<(KSEL + 255)/256, 256, 0, stream>>>(g_rank, starts, ends, top_idx);

  k_gather<<<KSEL, 256, 0, stream>>>(top_idx, flatbf, hemb, wembP, starts, ends, cscores, spk_ids,
                                     ment, mscore, mspk);

  // fast antecedent scores
  k_mfma<<<dim3((MENTD+127)/128, (KSEL+127)/128), 256, 0, stream>>>(
      ment, nullptr, fastT, KSEL, MENTD, KPAD, KPAD, fbP, nullptr,
      nullptr, 0, srcb, KPAD, KPAD, 0, nullptr, nullptr);
  k_mfma<<<dim3((KSEL+127)/128, (KSEL+127)/128), 256, 0, stream>>>(
      srcb, nullptr, ment, KSEL, KSEL, KPAD, KPAD, nullptr, mscore,
      fastm, KSEL, nullptr, 0, 0, MF_MASK, nullptr, nullptr);
  k_f3<<<(KSEL+3)/4, 256, 0, stream>>>(fastm, top_fast, antes);

  k_dsmall<<<18, 256, 0, stream>>>(ss_w1, ss_b1, spk_e, gen_e, dist_e, genre_id, comb);

  const u16* mcur = ment;
  for (int iter = 0; iter < 2; ++iter){
    k_mfma<<<dim3(8, (KSEL+127)/128), 256, 0, stream>>>(
        mcur, nullptr, ss1abT, KSEL, 1024, KPAD, KPAD, nullptr, nullptr,
        A_meb, 1024, nullptr, 0, 0, 0, nullptr, nullptr);
    k_d1_mfma<<<dim3(2, (NPAIR + 127)/128), 256, 0, stream>>>(
        NPAIR, mcur, antes, mspk, sspT, A_meb, comb, bufH1);
    k_mfma_rowdot<<<(NPAIR + 127)/128, 256, 0, stream>>>(bufH1, ss2T, NPAIR, ss_b2, ss_w3, ss_b3,
                                                         top_fast, ante_sc);
    if (iter == 0){
      k_d4a<<<KSEL, 256, 0, stream>>>(ante_sc, antes, mcur, att_bf);
      k_mfma<<<dim3((MENTD+127)/128, (KSEL+127)/128), 256, 0, stream>>>(
          ment, att_bf, gateTall, KSEL, MENTD, 2*KPAD, KPAD, gbP, nullptr,
          nullptr, 0, mentB, KPAD, KPAD, MF_GATE, att_bf, ment);
      mcur = mentB;
    }
  }

  k_out<<<(KSEL*41 + 255)/256, 256, 0, stream>>>(ante_sc, out);
}